// Round 2
// baseline (5025.484 us; speedup 1.0000x reference)
//
#include <hip/hip_runtime.h>
#include <math.h>

constexpr int N_ = 8192;
constexpr int NK_ = 16384;
constexpr int D_ = 768;
constexpr int E_ = 8;
constexpr int CAP_ = 4096;
constexpr float NEG_ = -3.402823466e38f;

// ---------------- init ----------------
__global__ void k_init(float* accs, int* ints) {
  int t = threadIdx.x;
  if (t < 32) accs[t] = 0.f;
  if (t < 32) ints[t] = 0;
}

// ---------------- router ----------------
// 4 tokens per block (wave per token). Computes logits = x @ gate_w.T on the fly,
// top-2 (jax tie-break: lowest index), softmax stats, aux accumulators, counts.
__global__ __launch_bounds__(256) void k_router(
    const float* __restrict__ x, const float* __restrict__ gw,
    float* __restrict__ tv, float* __restrict__ tp, int* __restrict__ ti,
    float* __restrict__ accs, int* __restrict__ cnt,
    float* __restrict__ idx_out) {
  __shared__ float gws[8 * 768];
  __shared__ float rS1[8], rS2[8], rz[1];
  __shared__ int rc[8];
  int tid = threadIdx.x;
  for (int i = tid; i < 8 * 768; i += 256) gws[i] = gw[i];
  if (tid < 8) { rS1[tid] = 0.f; rS2[tid] = 0.f; rc[tid] = 0; }
  if (tid == 0) rz[0] = 0.f;
  __syncthreads();
  int wid = tid >> 6, lane = tid & 63;
  int n = blockIdx.x * 4 + wid;
  const float* xr = x + (size_t)n * D_;
  float acc[8];
#pragma unroll
  for (int e = 0; e < 8; ++e) acc[e] = 0.f;
  for (int c = 0; c < D_; c += 64) {
    float xv = xr[c + lane];
#pragma unroll
    for (int e = 0; e < 8; ++e) acc[e] = fmaf(xv, gws[e * D_ + c + lane], acc[e]);
  }
#pragma unroll
  for (int e = 0; e < 8; ++e) {
#pragma unroll
    for (int off = 32; off >= 1; off >>= 1) acc[e] += __shfl_xor(acc[e], off, 64);
  }
  if (lane == 0) {
    float v1 = NEG_; int i1 = 0;
#pragma unroll
    for (int e = 0; e < 8; ++e) if (acc[e] > v1) { v1 = acc[e]; i1 = e; }
    float v2 = NEG_; int i2 = 0;
#pragma unroll
    for (int e = 0; e < 8; ++e) if (e != i1 && acc[e] > v2) { v2 = acc[e]; i2 = e; }
    float den = 0.f; float pe[8];
#pragma unroll
    for (int e = 0; e < 8; ++e) { pe[e] = expf(acc[e] - v1); den += pe[e]; }
    float inv = 1.f / den;
#pragma unroll
    for (int e = 0; e < 8; ++e) atomicAdd(&rS1[e], pe[e] * inv);
    float z = v1 + logf(den);
    atomicAdd(&rz[0], z * z);
    float t2 = expf(v2 - v1);
    float p1 = 1.f / (1.f + t2);
    float p2 = t2 / (1.f + t2);
    atomicAdd(&rS2[i1], p1);
    atomicAdd(&rS2[i2], p2);
    atomicAdd(&rc[i1], 1);
    atomicAdd(&rc[i2], 1);
    int s0 = n * 2;
    tv[s0] = v1; tv[s0 + 1] = v2;
    tp[s0] = p1; tp[s0 + 1] = p2;
    ti[s0] = i1; ti[s0 + 1] = i2;
    // harness reads the int64 output chunk as float32 values
    idx_out[s0] = (float)i1;
    idx_out[s0 + 1] = (float)i2;
  }
  __syncthreads();
  if (tid < 8) {
    atomicAdd(&accs[tid], rS1[tid]);
    atomicAdd(&accs[8 + tid], rS2[tid]);
    atomicAdd(&cnt[tid], rc[tid]);
  }
  if (tid == 0) atomicAdd(&accs[16], rz[0]);
}

// ---------------- keep (capacity) ----------------
__global__ void k_keep(const float* __restrict__ tv, const int* __restrict__ ti,
                       const int* __restrict__ cnt, int* __restrict__ keep,
                       int* __restrict__ kcnt, float* __restrict__ accs) {
  __shared__ int kc[8]; __shared__ int ks[1];
  int tid = threadIdx.x;
  if (tid < 8) kc[tid] = 0;
  if (tid == 0) ks[0] = 0;
  __syncthreads();
  int s = blockIdx.x * 256 + tid;
  int e = ti[s];
  int kp;
  if (cnt[e] <= CAP_) kp = 1;   // common case: nothing dropped
  else {                        // rare: exact top-C rank with index tie-break
    float p = tv[s];
    int rank = 0;
    for (int j = 0; j < NK_; ++j) {
      if (ti[j] == e) {
        float pj = tv[j];
        if (pj > p || (pj == p && j < s)) ++rank;
      }
    }
    kp = (rank < CAP_) ? 1 : 0;
  }
  keep[s] = kp;
  atomicAdd(&kc[e], kp);
  atomicAdd(&ks[0], kp);
  __syncthreads();
  if (tid < 8) atomicAdd(&kcnt[tid], kc[tid]);
  if (tid == 0) atomicAdd(&accs[17], (float)ks[0]);
}

__global__ void k_prefix(const int* __restrict__ kcnt, int* __restrict__ koff) {
  if (threadIdx.x == 0) {
    int o = 0;
    for (int e = 0; e < 8; ++e) { koff[e] = o; o += kcnt[e]; }
  }
}

__global__ void k_scatter(const int* __restrict__ keep, const int* __restrict__ ti,
                          const int* __restrict__ koff, int* __restrict__ kpos,
                          int* __restrict__ bucket) {
  int s = blockIdx.x * 256 + threadIdx.x;
  if (keep[s]) {
    int e = ti[s];
    int pos = atomicAdd(&kpos[e], 1);
    bucket[koff[e] + pos] = s;
  }
}

__global__ void k_weights(const float* __restrict__ tp, const int* __restrict__ keep,
                          float* __restrict__ wb) {
  int n = blockIdx.x * 256 + threadIdx.x;
  if (n < N_) {
    int s = n * 2;
    float t0 = keep[s] ? tp[s] : 0.f;
    float t1 = keep[s + 1] ? tp[s + 1] : 0.f;
    float d = fmaxf(t0 + t1, 1e-12f);
    wb[s] = t0 / d; wb[s + 1] = t1 / d;
  }
}

__global__ void k_zero_dropped(const int* __restrict__ keep, float* __restrict__ sel) {
  int s = blockIdx.x;
  if (keep[s]) return;
  float4 z = {0.f, 0.f, 0.f, 0.f};
  *(float4*)(sel + (size_t)s * D_ + threadIdx.x * 4) = z;
}

// ---------------- FFN1: gu = (2x) @ w13[e].T, swiglu epilogue ----------------
// grid.x: 64 tiles of 32 h-pairs; grid.y: expert(3b) x row-tile(6b)
__global__ __launch_bounds__(256) void k_ffn1(
    const float* __restrict__ x, const float* __restrict__ w13,
    const int* __restrict__ bucket, const int* __restrict__ kcnt,
    const int* __restrict__ koff, float* __restrict__ swig) {
  const int e = blockIdx.y >> 6;
  const int rt = blockIdx.y & 63;
  const int rows = kcnt[e];
  const int row0 = rt << 6;
  if (row0 >= rows) return;
  const int off = koff[e];
  __shared__ float As[16][68];
  __shared__ float Bs[16][68];
  __shared__ int tok[64];
  const int tid = threadIdx.x;
  if (tid < 64) {
    int r = row0 + tid;
    int br = (r < rows) ? (off + r) : off;
    tok[tid] = bucket[br] >> 1;
  }
  __syncthreads();
  const int lr = tid >> 2, lc = (tid & 3) << 2;
  const int bx = blockIdx.x;
  const int h = (bx << 5) + (lr >> 1);
  const int brow = (lr & 1) ? (2048 + h) : h;
  const float* Brow = w13 + (size_t)e * (4096 * 768) + (size_t)brow * D_ + lc;
  const float* Arow = x + (size_t)tok[lr] * D_ + lc;
  const int ty = tid >> 4, tx = tid & 15;
  float acc[4][4];
#pragma unroll
  for (int i = 0; i < 4; ++i)
#pragma unroll
    for (int j = 0; j < 4; ++j) acc[i][j] = 0.f;
  for (int k0 = 0; k0 < D_; k0 += 16) {
    float4 av = *(const float4*)(Arow + k0);
    float4 bv = *(const float4*)(Brow + k0);
    As[lc + 0][lr] = 2.f * av.x; As[lc + 1][lr] = 2.f * av.y;
    As[lc + 2][lr] = 2.f * av.z; As[lc + 3][lr] = 2.f * av.w;
    Bs[lc + 0][lr] = bv.x; Bs[lc + 1][lr] = bv.y;
    Bs[lc + 2][lr] = bv.z; Bs[lc + 3][lr] = bv.w;
    __syncthreads();
#pragma unroll
    for (int kk = 0; kk < 16; ++kk) {
      const float4 a = *(const float4*)&As[kk][ty << 2];
      const float4 b = *(const float4*)&Bs[kk][tx << 2];
      const float aa[4] = {a.x, a.y, a.z, a.w};
      const float bb[4] = {b.x, b.y, b.z, b.w};
#pragma unroll
      for (int i = 0; i < 4; ++i)
#pragma unroll
        for (int j = 0; j < 4; ++j) acc[i][j] = fmaf(aa[i], bb[j], acc[i][j]);
    }
    __syncthreads();
  }
  const int p = (bx << 5) + (tx << 1);
#pragma unroll
  for (int i = 0; i < 4; ++i) {
    int r = row0 + (ty << 2) + i;
    if (r < rows) {
      float g0 = acc[i][0], u0 = acc[i][1], g1 = acc[i][2], u1 = acc[i][3];
      float s0 = g0 / (1.f + expf(-g0)) * u0;
      float s1 = g1 / (1.f + expf(-g1)) * u1;
      size_t base = (size_t)(off + r) * 2048 + p;
      swig[base] = s0; swig[base + 1] = s1;
    }
  }
}

// ---------------- FFN2: y = x + swig @ w2[e].T ----------------
__global__ __launch_bounds__(256) void k_ffn2(
    const float* __restrict__ x, const float* __restrict__ w2,
    const float* __restrict__ swig, const int* __restrict__ bucket,
    const int* __restrict__ kcnt, const int* __restrict__ koff,
    float* __restrict__ sel) {
  const int e = blockIdx.y >> 6;
  const int rt = blockIdx.y & 63;
  const int rows = kcnt[e];
  const int row0 = rt << 6;
  if (row0 >= rows) return;
  const int off = koff[e];
  __shared__ float As[16][68];
  __shared__ float Bs[16][68];
  __shared__ int slt[64];
  const int tid = threadIdx.x;
  if (tid < 64) {
    int r = row0 + tid;
    slt[tid] = (r < rows) ? bucket[off + r] : 0;
  }
  __syncthreads();
  const int lr = tid >> 2, lc = (tid & 3) << 2;
  const int rr = (row0 + lr < rows) ? (row0 + lr) : row0;
  const float* Arow = swig + (size_t)(off + rr) * 2048 + lc;
  const int bx = blockIdx.x;
  const float* Brow = w2 + (size_t)e * (768 * 2048) + (size_t)((bx << 6) + lr) * 2048 + lc;
  const int ty = tid >> 4, tx = tid & 15;
  float acc[4][4];
#pragma unroll
  for (int i = 0; i < 4; ++i)
#pragma unroll
    for (int j = 0; j < 4; ++j) acc[i][j] = 0.f;
  for (int k0 = 0; k0 < 2048; k0 += 16) {
    float4 av = *(const float4*)(Arow + k0);
    float4 bv = *(const float4*)(Brow + k0);
    As[lc + 0][lr] = av.x; As[lc + 1][lr] = av.y;
    As[lc + 2][lr] = av.z; As[lc + 3][lr] = av.w;
    Bs[lc + 0][lr] = bv.x; Bs[lc + 1][lr] = bv.y;
    Bs[lc + 2][lr] = bv.z; Bs[lc + 3][lr] = bv.w;
    __syncthreads();
#pragma unroll
    for (int kk = 0; kk < 16; ++kk) {
      const float4 a = *(const float4*)&As[kk][ty << 2];
      const float4 b = *(const float4*)&Bs[kk][tx << 2];
      const float aa[4] = {a.x, a.y, a.z, a.w};
      const float bb[4] = {b.x, b.y, b.z, b.w};
#pragma unroll
      for (int i = 0; i < 4; ++i)
#pragma unroll
        for (int j = 0; j < 4; ++j) acc[i][j] = fmaf(aa[i], bb[j], acc[i][j]);
    }
    __syncthreads();
  }
#pragma unroll
  for (int i = 0; i < 4; ++i) {
    int r = row0 + (ty << 2) + i;
    if (r < rows) {
      int s = slt[(ty << 2) + i];
      int t = s >> 1;
      size_t cb = (size_t)(bx << 6) + (tx << 2);
      const float4 xa = *(const float4*)(x + (size_t)t * D_ + cb);
      float4 o;
      o.x = xa.x + acc[i][0]; o.y = xa.y + acc[i][1];
      o.z = xa.z + acc[i][2]; o.w = xa.w + acc[i][3];
      *(float4*)(sel + (size_t)s * D_ + cb) = o;
    }
  }
}

// ---------------- generic NT GEMM, 64x64x16 tile ----------------
// EPI 0: store; 1: exact gelu; 2: (add + acc) * km[row]
template <int EPI>
__global__ __launch_bounds__(256) void k_gemm(
    const float* __restrict__ A, int lda, const float* __restrict__ B, int ldb,
    float* __restrict__ Cp, int ldc, int Kdim,
    const float* __restrict__ addp, const int* __restrict__ km) {
  __shared__ float As[16][68];
  __shared__ float Bs[16][68];
  const int tid = threadIdx.x;
  const int row0 = blockIdx.y << 6, col0 = blockIdx.x << 6;
  const int lr = tid >> 2, lc = (tid & 3) << 2;
  const float* Arow = A + (size_t)(row0 + lr) * lda + lc;
  const float* Brow = B + (size_t)(col0 + lr) * ldb + lc;
  const int ty = tid >> 4, tx = tid & 15;
  float acc[4][4];
#pragma unroll
  for (int i = 0; i < 4; ++i)
#pragma unroll
    for (int j = 0; j < 4; ++j) acc[i][j] = 0.f;
  for (int k0 = 0; k0 < Kdim; k0 += 16) {
    float4 av = *(const float4*)(Arow + k0);
    float4 bv = *(const float4*)(Brow + k0);
    As[lc + 0][lr] = av.x; As[lc + 1][lr] = av.y;
    As[lc + 2][lr] = av.z; As[lc + 3][lr] = av.w;
    Bs[lc + 0][lr] = bv.x; Bs[lc + 1][lr] = bv.y;
    Bs[lc + 2][lr] = bv.z; Bs[lc + 3][lr] = bv.w;
    __syncthreads();
#pragma unroll
    for (int kk = 0; kk < 16; ++kk) {
      const float4 a = *(const float4*)&As[kk][ty << 2];
      const float4 b = *(const float4*)&Bs[kk][tx << 2];
      const float aa[4] = {a.x, a.y, a.z, a.w};
      const float bb[4] = {b.x, b.y, b.z, b.w};
#pragma unroll
      for (int i = 0; i < 4; ++i)
#pragma unroll
        for (int j = 0; j < 4; ++j) acc[i][j] = fmaf(aa[i], bb[j], acc[i][j]);
    }
    __syncthreads();
  }
#pragma unroll
  for (int i = 0; i < 4; ++i) {
    int r = row0 + (ty << 2) + i;
    size_t base = (size_t)r * ldc + col0 + (tx << 2);
    float v[4];
#pragma unroll
    for (int j = 0; j < 4; ++j) v[j] = acc[i][j];
    if (EPI == 1) {
#pragma unroll
      for (int j = 0; j < 4; ++j)
        v[j] = 0.5f * v[j] * (1.f + erff(v[j] * 0.70710678118654752f));
    } else if (EPI == 2) {
      const float4 ad = *(const float4*)(addp + base);
      float kmv = km[r] ? 1.f : 0.f;
      v[0] = (ad.x + v[0]) * kmv; v[1] = (ad.y + v[1]) * kmv;
      v[2] = (ad.z + v[2]) * kmv; v[3] = (ad.w + v[3]) * kmv;
    }
    float4 o; o.x = v[0]; o.y = v[1]; o.z = v[2]; o.w = v[3];
    *(float4*)(Cp + base) = o;
  }
}

// ---------------- per-token 2x2 attention + cat build ----------------
__global__ __launch_bounds__(256) void k_scores_cat(
    const float* __restrict__ Qb, const float* __restrict__ Ktb,
    const float* __restrict__ Mb, const float* __restrict__ sel,
    const int* __restrict__ keep, float* __restrict__ cat) {
  int tid = threadIdx.x;
  int wid = tid >> 6, lane = tid & 63;
  int n = blockIdx.x * 4 + wid;
  size_t r0 = (size_t)(n * 2) * D_;
  size_t r1 = r0 + D_;
  float s00 = 0, s01 = 0, s10 = 0, s11 = 0;
  for (int c = lane; c < D_; c += 64) {
    float q0 = Qb[r0 + c], q1 = Qb[r1 + c];
    float k0 = Ktb[r0 + c], k1 = Ktb[r1 + c];
    s00 = fmaf(q0, k0, s00); s01 = fmaf(q0, k1, s01);
    s10 = fmaf(q1, k0, s10); s11 = fmaf(q1, k1, s11);
  }
#pragma unroll
  for (int off = 32; off >= 1; off >>= 1) {
    s00 += __shfl_xor(s00, off, 64);
    s01 += __shfl_xor(s01, off, 64);
    s10 += __shfl_xor(s10, off, 64);
    s11 += __shfl_xor(s11, off, 64);
  }
  const float scl = 27.712812921102035f;  // sqrt(768)
  s00 /= scl; s01 /= scl; s10 /= scl; s11 /= scl;
  int km0 = keep[n * 2], km1 = keep[n * 2 + 1];
  float a00, a01, a10, a11;
  {
    int v0 = km0 & km0, v1 = km0 & km1;
    float t0 = v0 ? s00 : NEG_, t1 = v1 ? s01 : NEG_;
    float m = fmaxf(t0, t1);
    float e0 = expf(t0 - m), e1 = expf(t1 - m);
    float sm = e0 + e1;
    float b0 = (e0 / sm) * (v0 ? 1.f : 0.f);
    float b1 = (e1 / sm) * (v1 ? 1.f : 0.f);
    float d = fmaxf(b0 + b1, 1e-12f);
    a00 = b0 / d; a01 = b1 / d;
  }
  {
    int v0 = km1 & km0, v1 = km1 & km1;
    float t0 = v0 ? s10 : NEG_, t1 = v1 ? s11 : NEG_;
    float m = fmaxf(t0, t1);
    float e0 = expf(t0 - m), e1 = expf(t1 - m);
    float sm = e0 + e1;
    float b0 = (e0 / sm) * (v0 ? 1.f : 0.f);
    float b1 = (e1 / sm) * (v1 ? 1.f : 0.f);
    float d = fmaxf(b0 + b1, 1e-12f);
    a10 = b0 / d; a11 = b1 / d;
  }
  size_t c0 = (size_t)(n * 2) * 1536;
  size_t c1 = c0 + 1536;
  for (int c = lane; c < D_; c += 64) {
    float m0 = Mb[r0 + c], m1 = Mb[r1 + c];
    cat[c0 + 768 + c] = fmaf(a00, m0, a01 * m1);
    cat[c1 + 768 + c] = fmaf(a10, m0, a11 * m1);
    cat[c0 + c] = sel[r0 + c];
    cat[c1 + c] = sel[r1 + c];
  }
}

// ---------------- weighted combine over K=2 ----------------
__global__ void k_combine(const float* __restrict__ refined, const float* __restrict__ wb,
                          float* __restrict__ fin) {
  int n = blockIdx.x;
  int t = threadIdx.x;
  float w0 = wb[n * 2], w1 = wb[n * 2 + 1];
  const float4 r0 = *(const float4*)(refined + (size_t)(n * 2) * D_ + t * 4);
  const float4 r1 = *(const float4*)(refined + (size_t)(n * 2 + 1) * D_ + t * 4);
  float4 o;
  o.x = r0.x * w0 + r1.x * w1; o.y = r0.y * w0 + r1.y * w1;
  o.z = r0.z * w0 + r1.z * w1; o.w = r0.w * w0 + r1.w * w1;
  *(float4*)(fin + (size_t)n * D_ + t * 4) = o;
}

__global__ void k_aux(const float* __restrict__ accs, float* __restrict__ outp) {
  if (threadIdx.x == 0) {
    float bal = 0.f;
    for (int e = 0; e < 8; ++e) bal += (accs[e] / (float)N_) * (accs[8 + e] / (float)N_);
    bal *= (float)E_;
    float z = accs[16] / (float)N_;
    float km = accs[17] / (float)NK_;
    outp[0] = 0.01f * bal + 0.001f * z + 0.001f * (1.f - km);
  }
}

// ---------------- host ----------------
extern "C" void kernel_launch(void* const* d_in, const int* in_sizes, int n_in,
                              void* d_out, int out_size, void* d_ws, size_t ws_size,
                              hipStream_t stream) {
  (void)in_sizes; (void)n_in; (void)ws_size; (void)out_size;
  const float* x = (const float*)d_in[0];
  const float* gate_w = (const float*)d_in[1];
  const float* w13 = (const float*)d_in[2];
  const float* w2 = (const float*)d_in[3];
  const float* msg_w = (const float*)d_in[4];
  const float* q_w = (const float*)d_in[5];
  const float* k_w = (const float*)d_in[6];
  const float* o_w = (const float*)d_in[7];
  const float* upd_w1 = (const float*)d_in[8];
  const float* upd_w2 = (const float*)d_in[9];

  float* ws = (float*)d_ws;
  float* accs = ws;                    // 32 floats
  int* ints = (int*)(ws + 32);         // 32 ints
  int* cnt = ints;
  int* kcnt = ints + 8;
  int* koff = ints + 16;
  int* kpos = ints + 24;
  float* tv = ws + 64;
  float* tp = ws + 16448;
  float* wb = ws + 32832;
  int* ti = (int*)(ws + 49216);
  int* keep = (int*)(ws + 65600);
  int* bucket = (int*)(ws + 81984);
  float* swig = ws + 98560;            // 33,554,432 f (also cat, then fused_in)
  float* cat = swig;
  float* fin = swig;
  float* sel = ws + 33652992ll;        // 12,582,912 f
  float* Mb = ws + 46235904ll;         // 12,582,912 f (later: refined)
  float* refined = Mb;
  float* Qb = ws + 58818816ll;         // 12,582,912 f
  float* Ktb = ws + 71401728ll;        // 12,582,912 f
  float* updh = Qb;                    // 25,165,824 f overlays Q..Kt

  float* fused = (float*)d_out;
  float* aux = fused + 6291456;
  float* idx_out = fused + 6291457;    // int64 chunk is read back as f32 values

  k_init<<<1, 64, 0, stream>>>(accs, ints);
  k_router<<<2048, 256, 0, stream>>>(x, gate_w, tv, tp, ti, accs, cnt, idx_out);
  k_keep<<<64, 256, 0, stream>>>(tv, ti, cnt, keep, kcnt, accs);
  k_prefix<<<1, 64, 0, stream>>>(kcnt, koff);
  k_scatter<<<64, 256, 0, stream>>>(keep, ti, koff, kpos, bucket);
  k_weights<<<32, 256, 0, stream>>>(tp, keep, wb);
  k_zero_dropped<<<16384, 192, 0, stream>>>(keep, sel);
  k_ffn1<<<dim3(64, 512), 256, 0, stream>>>(x, w13, bucket, kcnt, koff, swig);
  k_ffn2<<<dim3(12, 512), 256, 0, stream>>>(x, w2, swig, bucket, kcnt, koff, sel);
  k_gemm<0><<<dim3(12, 256), 256, 0, stream>>>(sel, 768, msg_w, 768, Mb, 768, 768, nullptr, nullptr);
  k_gemm<0><<<dim3(12, 256), 256, 0, stream>>>(sel, 768, q_w, 768, Qb, 768, 768, nullptr, nullptr);
  k_gemm<0><<<dim3(12, 256), 256, 0, stream>>>(Mb, 768, k_w, 768, Ktb, 768, 768, nullptr, nullptr);
  k_scores_cat<<<2048, 256, 0, stream>>>(Qb, Ktb, Mb, sel, keep, cat);
  k_gemm<1><<<dim3(24, 256), 256, 0, stream>>>(cat, 1536, upd_w1, 1536, updh, 1536, 1536, nullptr, nullptr);
  k_gemm<2><<<dim3(12, 256), 256, 0, stream>>>(updh, 1536, upd_w2, 1536, refined, 768, 1536, sel, keep);
  k_combine<<<8192, 192, 0, stream>>>(refined, wb, fin);
  k_gemm<0><<<dim3(12, 128), 256, 0, stream>>>(fin, 768, o_w, 768, fused, 768, 768, nullptr, nullptr);
  k_aux<<<1, 64, 0, stream>>>(accs, aux);
}

// Round 8
// 1077.848 us; speedup vs baseline: 4.6625x; 4.6625x over previous
//
#include <hip/hip_runtime.h>
#include <math.h>

constexpr int N_ = 8192;
constexpr int NK_ = 16384;
constexpr int D_ = 768;
constexpr int E_ = 8;
constexpr int CAP_ = 4096;
constexpr float NEG_ = -3.402823466e38f;

typedef unsigned short ushortT;
typedef __attribute__((ext_vector_type(8))) short short8v;
typedef __attribute__((ext_vector_type(4))) float float4v;
typedef __attribute__((ext_vector_type(4))) unsigned short ushort4v;
typedef __attribute__((ext_vector_type(2))) unsigned short ushort2v;

// ushort-region offsets (in ushort elements) from ub = (ushortT*)(ws + 98560)
constexpr long long O_W13 = 0;          // 25,165,824  (catb overlays after ffn1)
constexpr long long O_CAT = 0;
constexpr long long O_W2  = 25165824;   // 12,582,912
constexpr long long O_MSG = 37748736;   // 589,824
constexpr long long O_Q   = 38338560;
constexpr long long O_K   = 38928384;
constexpr long long O_OW  = 39518208;
constexpr long long O_U1  = 40108032;   // 2,359,296
constexpr long long O_U2  = 42467328;   // 1,179,648
constexpr long long O_XG  = 43646976;   // 12,582,912 (updhb overlays after ffn2)
constexpr long long O_UPDH= 43646976;   // 25,165,824
constexpr long long O_SWIG= 56229888;   // 33,554,432
constexpr long long O_FIN = 68812800;   // 6,291,456
constexpr long long O_SELB= 89784320;   // 12,582,912
constexpr long long O_MBB = 102367232;  // 12,582,912
constexpr long long O_QBB = 114950144;  // 12,582,912 (refinedb overlays)
constexpr long long O_REF = 114950144;
constexpr long long O_KTB = 127533056;  // 12,582,912

__device__ inline ushortT f2bf(float f) {
  unsigned u = __float_as_uint(f);
  unsigned r = (u + 0x7FFFu + ((u >> 16) & 1u)) >> 16;
  return (ushortT)r;
}
__device__ inline float bf2f(ushortT h) {
  return __uint_as_float(((unsigned)h) << 16);
}

// ---------------- init ----------------
__global__ void k_init(float* accs, int* ints) {
  int t = threadIdx.x;
  if (t < 32) accs[t] = 0.f;
  if (t < 32) ints[t] = 0;
}

// ---------------- f32 -> bf16 convert ----------------
__global__ void k_cvt(const float* __restrict__ in, ushortT* __restrict__ out, int n4) {
  for (int i = blockIdx.x * 256 + threadIdx.x; i < n4; i += gridDim.x * 256) {
    float4 v = *(const float4*)(in + (size_t)i * 4);
    ushort4v o = {f2bf(v.x), f2bf(v.y), f2bf(v.z), f2bf(v.w)};
    *(ushort4v*)(out + (size_t)i * 4) = o;
  }
}

// ---------------- router (fp32) ----------------
__global__ __launch_bounds__(256) void k_router(
    const float* __restrict__ x, const float* __restrict__ gw,
    float* __restrict__ tv, float* __restrict__ tp, int* __restrict__ ti,
    float* __restrict__ accs, int* __restrict__ cnt,
    float* __restrict__ idx_out) {
  __shared__ float gws[8 * 768];
  __shared__ float rS1[8], rS2[8], rz[1];
  __shared__ int rc[8];
  int tid = threadIdx.x;
  for (int i = tid; i < 8 * 768; i += 256) gws[i] = gw[i];
  if (tid < 8) { rS1[tid] = 0.f; rS2[tid] = 0.f; rc[tid] = 0; }
  if (tid == 0) rz[0] = 0.f;
  __syncthreads();
  int wid = tid >> 6, lane = tid & 63;
  int n = blockIdx.x * 4 + wid;
  const float* xr = x + (size_t)n * D_;
  float acc[8];
#pragma unroll
  for (int e = 0; e < 8; ++e) acc[e] = 0.f;
  for (int c = 0; c < D_; c += 64) {
    float xv = xr[c + lane];
#pragma unroll
    for (int e = 0; e < 8; ++e) acc[e] = fmaf(xv, gws[e * D_ + c + lane], acc[e]);
  }
#pragma unroll
  for (int e = 0; e < 8; ++e) {
#pragma unroll
    for (int off = 32; off >= 1; off >>= 1) acc[e] += __shfl_xor(acc[e], off, 64);
  }
  if (lane == 0) {
    float v1 = NEG_; int i1 = 0;
#pragma unroll
    for (int e = 0; e < 8; ++e) if (acc[e] > v1) { v1 = acc[e]; i1 = e; }
    float v2 = NEG_; int i2 = 0;
#pragma unroll
    for (int e = 0; e < 8; ++e) if (e != i1 && acc[e] > v2) { v2 = acc[e]; i2 = e; }
    float den = 0.f; float pe[8];
#pragma unroll
    for (int e = 0; e < 8; ++e) { pe[e] = expf(acc[e] - v1); den += pe[e]; }
    float inv = 1.f / den;
#pragma unroll
    for (int e = 0; e < 8; ++e) atomicAdd(&rS1[e], pe[e] * inv);
    float z = v1 + logf(den);
    atomicAdd(&rz[0], z * z);
    float t2 = expf(v2 - v1);
    float p1 = 1.f / (1.f + t2);
    float p2 = t2 / (1.f + t2);
    atomicAdd(&rS2[i1], p1);
    atomicAdd(&rS2[i2], p2);
    atomicAdd(&rc[i1], 1);
    atomicAdd(&rc[i2], 1);
    int s0 = n * 2;
    tv[s0] = v1; tv[s0 + 1] = v2;
    tp[s0] = p1; tp[s0 + 1] = p2;
    ti[s0] = i1; ti[s0 + 1] = i2;
    idx_out[s0] = (float)i1;
    idx_out[s0 + 1] = (float)i2;
  }
  __syncthreads();
  if (tid < 8) {
    atomicAdd(&accs[tid], rS1[tid]);
    atomicAdd(&accs[8 + tid], rS2[tid]);
    atomicAdd(&cnt[tid], rc[tid]);
  }
  if (tid == 0) atomicAdd(&accs[16], rz[0]);
}

// ---------------- keep (capacity) ----------------
__global__ void k_keep(const float* __restrict__ tv, const int* __restrict__ ti,
                       const int* __restrict__ cnt, int* __restrict__ keep,
                       int* __restrict__ kcnt, float* __restrict__ accs) {
  __shared__ int kc[8]; __shared__ int ks[1];
  int tid = threadIdx.x;
  if (tid < 8) kc[tid] = 0;
  if (tid == 0) ks[0] = 0;
  __syncthreads();
  int s = blockIdx.x * 256 + tid;
  int e = ti[s];
  int kp;
  if (cnt[e] <= CAP_) kp = 1;
  else {
    float p = tv[s];
    int rank = 0;
    for (int j = 0; j < NK_; ++j) {
      if (ti[j] == e) {
        float pj = tv[j];
        if (pj > p || (pj == p && j < s)) ++rank;
      }
    }
    kp = (rank < CAP_) ? 1 : 0;
  }
  keep[s] = kp;
  atomicAdd(&kc[e], kp);
  atomicAdd(&ks[0], kp);
  __syncthreads();
  if (tid < 8) atomicAdd(&kcnt[tid], kc[tid]);
  if (tid == 0) atomicAdd(&accs[17], (float)ks[0]);
}

__global__ void k_prefix(const int* __restrict__ kcnt, int* __restrict__ koff) {
  if (threadIdx.x == 0) {
    int o = 0;
    for (int e = 0; e < 8; ++e) { koff[e] = o; o += kcnt[e]; }
  }
}

__global__ void k_scatter(const int* __restrict__ keep, const int* __restrict__ ti,
                          const int* __restrict__ koff, int* __restrict__ kpos,
                          int* __restrict__ bucket) {
  int s = blockIdx.x * 256 + threadIdx.x;
  if (keep[s]) {
    int e = ti[s];
    int pos = atomicAdd(&kpos[e], 1);
    bucket[koff[e] + pos] = s;
  }
}

__global__ void k_weights(const float* __restrict__ tp, const int* __restrict__ keep,
                          float* __restrict__ wb) {
  int n = blockIdx.x * 256 + threadIdx.x;
  if (n < N_) {
    int s = n * 2;
    float t0 = keep[s] ? tp[s] : 0.f;
    float t1 = keep[s + 1] ? tp[s + 1] : 0.f;
    float d = fmaxf(t0 + t1, 1e-12f);
    wb[s] = t0 / d; wb[s + 1] = t1 / d;
  }
}

// ---------------- gather A rows for ffn1: xg[r] = bf16(2*x[bucket[r]>>1]) ----------------
__global__ void k_gather(const float* __restrict__ x, const int* __restrict__ bucket,
                         const int* __restrict__ kcnt, const int* __restrict__ koff,
                         ushortT* __restrict__ xg) {
  int r = blockIdx.x;
  int t = threadIdx.x;  // 192
  int total = koff[7] + kcnt[7];
  size_t ob = (size_t)r * D_ + t * 4;
  if (r < total) {
    int tok = bucket[r] >> 1;
    float4 v = *(const float4*)(x + (size_t)tok * D_ + t * 4);
    ushort4v o = {f2bf(2.f * v.x), f2bf(2.f * v.y), f2bf(2.f * v.z), f2bf(2.f * v.w)};
    *(ushort4v*)(xg + ob) = o;
  } else {
    ushort4v z = {0, 0, 0, 0};
    *(ushort4v*)(xg + ob) = z;
  }
}

__global__ void k_zero_dropped(const int* __restrict__ keep, ushortT* __restrict__ selb) {
  int s = blockIdx.x;
  if (keep[s]) return;
  ushort4v z = {0, 0, 0, 0};
  *(ushort4v*)(selb + (size_t)s * D_ + threadIdx.x * 4) = z;
}

// ---------------- generic bf16 MFMA GEMM (NT), 128x128 tile, BK=64 ----------------
// EPI: 0 = store bf16; 1 = ffn1 swiglu (pair cols, store swig bf16, expert rows);
//      2 = ffn2 scatter (sel = x + acc, bf16, expert rows); 3 = gelu store bf16;
//      4 = refined = (selb + acc)*keep, bf16; 5 = store f32
template <int EPI>
__global__ __launch_bounds__(256) void k_bgemm(
    const ushortT* __restrict__ A, int lda,
    const ushortT* __restrict__ B, int ldb, long long bstride,
    void* __restrict__ Cp, int ldc, int Kdim, int Mrows, int tpe,
    const int* __restrict__ kcnt, const int* __restrict__ koff,
    const int* __restrict__ bucket, const float* __restrict__ xf,
    const ushortT* __restrict__ selb, const int* __restrict__ keep) {
  __shared__ __align__(16) ushortT At[128 * 64];
  __shared__ __align__(16) ushortT Bt[128 * 64];
  __shared__ int slt[128];
  int e = 0, rt = blockIdx.y, rows = Mrows, off = 0;
  if (tpe) {
    e = blockIdx.y >> 5; rt = blockIdx.y & 31;
    rows = kcnt[e]; off = koff[e];
    if (rt * 128 >= rows) return;
  }
  const int row0 = rt * 128;
  const int col0 = blockIdx.x * 128;
  const ushortT* Bb = B + (size_t)e * bstride;

  const int tid = threadIdx.x;
  if (EPI == 2) {
    if (tid < 128) slt[tid] = (row0 + tid < rows) ? bucket[off + row0 + tid] : 0;
  }

  // staging: thread -> row=tid>>1, 4 chunks of 8 bf16 at chunk base (tid&1)*4
  const int srow = tid >> 1;
  const int sc0 = (tid & 1) * 4;
  int bsrcrow;
  if (EPI == 1) {
    int gcol = col0 + srow;
    bsrcrow = ((gcol & 1) << 11) + (gcol >> 1);   // gate rows [0,2048), up rows [2048,4096)
  } else {
    bsrcrow = col0 + srow;
  }
  const ushortT* Asrc = A + (size_t)(off + row0 + srow) * lda;
  const ushortT* Bsrc = Bb + (size_t)bsrcrow * ldb;
  const int sw = srow & 7;
  ushortT* Adst = At + srow * 64;
  ushortT* Bdst = Bt + srow * 64;

  const int l = tid & 63;
  const int wv = tid >> 6;
  const int wr = (wv >> 1) << 6;   // wave row offset in tile
  const int wc = (wv & 1) << 6;    // wave col offset
  const int fr = l & 15;
  const int kg = l >> 4;

  float4v acc[4][4];
#pragma unroll
  for (int m = 0; m < 4; ++m)
#pragma unroll
    for (int n = 0; n < 4; ++n) acc[m][n] = (float4v){0.f, 0.f, 0.f, 0.f};

  for (int k0 = 0; k0 < Kdim; k0 += 64) {
    __syncthreads();
#pragma unroll
    for (int j = 0; j < 4; ++j) {
      int c = sc0 + j;
      *(short8v*)(Adst + ((c ^ sw) << 3)) = *(const short8v*)(Asrc + k0 + (c << 3));
      *(short8v*)(Bdst + ((c ^ sw) << 3)) = *(const short8v*)(Bsrc + k0 + (c << 3));
    }
    __syncthreads();
#pragma unroll
    for (int kk = 0; kk < 2; ++kk) {
      short8v af[4], bf[4];
#pragma unroll
      for (int m = 0; m < 4; ++m) {
        int ar = wr + m * 16 + fr;
        af[m] = *(const short8v*)(At + ar * 64 + ((((kk << 2) + kg) ^ (ar & 7)) << 3));
        int br = wc + m * 16 + fr;
        bf[m] = *(const short8v*)(Bt + br * 64 + ((((kk << 2) + kg) ^ (br & 7)) << 3));
      }
#pragma unroll
      for (int m = 0; m < 4; ++m)
#pragma unroll
        for (int n = 0; n < 4; ++n)
          acc[m][n] = __builtin_amdgcn_mfma_f32_16x16x32_bf16(af[m], bf[n], acc[m][n], 0, 0, 0);
    }
  }

  // epilogue: lane holds D[row=(l>>4)*4+q][col=l&15] per fragment
#pragma unroll
  for (int m = 0; m < 4; ++m) {
#pragma unroll
    for (int q = 0; q < 4; ++q) {
      const int rl = wr + m * 16 + (kg << 2) + q;          // local row 0..127
      const bool rok = (tpe == 0) || (row0 + rl < rows);
#pragma unroll
      for (int n = 0; n < 4; ++n) {
        const int gcol = col0 + wc + n * 16 + fr;
        float v = acc[m][n][q];
        if (EPI == 0) {
          if (rok) ((ushortT*)Cp)[(size_t)(row0 + rl) * ldc + gcol] = f2bf(v);
        } else if (EPI == 1) {
          float pv = __shfl_xor(v, 1, 64);
          if ((l & 1) == 0) {
            float g = v, u = pv;
            float s = g / (1.f + expf(-g)) * u;
            if (rok)
              ((ushortT*)Cp)[(size_t)(off + row0 + rl) * ldc + (gcol >> 1)] = f2bf(s);
          }
        } else if (EPI == 2) {
          if (rok) {
            int slot = slt[rl];
            float xv = xf[(size_t)(slot >> 1) * D_ + gcol];
            ((ushortT*)Cp)[(size_t)slot * D_ + gcol] = f2bf(xv + v);
          }
        } else if (EPI == 3) {
          float gl = 0.5f * v * (1.f + erff(v * 0.70710678118654752f));
          ((ushortT*)Cp)[(size_t)(row0 + rl) * ldc + gcol] = f2bf(gl);
        } else if (EPI == 4) {
          int grow = row0 + rl;
          float sv = bf2f(selb[(size_t)grow * D_ + gcol]);
          float rr = (sv + v) * (keep[grow] ? 1.f : 0.f);
          ((ushortT*)Cp)[(size_t)grow * ldc + gcol] = f2bf(rr);
        } else if (EPI == 5) {
          ((float*)Cp)[(size_t)(row0 + rl) * ldc + gcol] = v;
        }
      }
    }
  }
}

// ---------------- per-token 2x2 attention + cat build (bf16 in/out) ----------------
__global__ __launch_bounds__(256) void k_scores_cat(
    const ushortT* __restrict__ Qb, const ushortT* __restrict__ Ktb,
    const ushortT* __restrict__ Mb, const ushortT* __restrict__ selb,
    const int* __restrict__ keep, ushortT* __restrict__ cat) {
  int tid = threadIdx.x;
  int wid = tid >> 6, lane = tid & 63;
  int n = blockIdx.x * 4 + wid;
  size_t r0 = (size_t)(n * 2) * D_;
  size_t r1 = r0 + D_;
  float s00 = 0, s01 = 0, s10 = 0, s11 = 0;
#pragma unroll
  for (int i = 0; i < 6; ++i) {
    int c = lane * 2 + i * 128;
    float q0a = bf2f(Qb[r0 + c]), q0b = bf2f(Qb[r0 + c + 1]);
    float q1a = bf2f(Qb[r1 + c]), q1b = bf2f(Qb[r1 + c + 1]);
    float k0a = bf2f(Ktb[r0 + c]), k0b = bf2f(Ktb[r0 + c + 1]);
    float k1a = bf2f(Ktb[r1 + c]), k1b = bf2f(Ktb[r1 + c + 1]);
    s00 += q0a * k0a + q0b * k0b; s01 += q0a * k1a + q0b * k1b;
    s10 += q1a * k0a + q1b * k0b; s11 += q1a * k1a + q1b * k1b;
  }
#pragma unroll
  for (int off = 32; off >= 1; off >>= 1) {
    s00 += __shfl_xor(s00, off, 64);
    s01 += __shfl_xor(s01, off, 64);
    s10 += __shfl_xor(s10, off, 64);
    s11 += __shfl_xor(s11, off, 64);
  }
  const float scl = 27.712812921102035f;  // sqrt(768)
  s00 /= scl; s01 /= scl; s10 /= scl; s11 /= scl;
  int km0 = keep[n * 2], km1 = keep[n * 2 + 1];
  float a00, a01, a10, a11;
  {
    int v0 = km0 & km0, v1 = km0 & km1;
    float t0 = v0 ? s00 : NEG_, t1 = v1 ? s01 : NEG_;
    float mx = fmaxf(t0, t1);
    float e0 = expf(t0 - mx), e1 = expf(t1 - mx);
    float sm = e0 + e1;
    float b0 = (e0 / sm) * (v0 ? 1.f : 0.f);
    float b1 = (e1 / sm) * (v1 ? 1.f : 0.f);
    float d = fmaxf(b0 + b1, 1e-12f);
    a00 = b0 / d; a01 = b1 / d;
  }
  {
    int v0 = km1 & km0, v1 = km1 & km1;
    float t0 = v0 ? s10 : NEG_, t1 = v1 ? s11 : NEG_;
    float mx = fmaxf(t0, t1);
    float e0 = expf(t0 - mx), e1 = expf(t1 - mx);
    float sm = e0 + e1;
    float b0 = (e0 / sm) * (v0 ? 1.f : 0.f);
    float b1 = (e1 / sm) * (v1 ? 1.f : 0.f);
    float d = fmaxf(b0 + b1, 1e-12f);
    a10 = b0 / d; a11 = b1 / d;
  }
  size_t c0 = (size_t)(n * 2) * 1536;
  size_t c1 = c0 + 1536;
#pragma unroll
  for (int i = 0; i < 6; ++i) {
    int c = lane * 2 + i * 128;
    float m0a = bf2f(Mb[r0 + c]), m0b = bf2f(Mb[r0 + c + 1]);
    float m1a = bf2f(Mb[r1 + c]), m1b = bf2f(Mb[r1 + c + 1]);
    ushort2v x0 = {f2bf(fmaf(a00, m0a, a01 * m1a)), f2bf(fmaf(a00, m0b, a01 * m1b))};
    ushort2v x1 = {f2bf(fmaf(a10, m0a, a11 * m1a)), f2bf(fmaf(a10, m0b, a11 * m1b))};
    *(ushort2v*)(cat + c0 + 768 + c) = x0;
    *(ushort2v*)(cat + c1 + 768 + c) = x1;
    *(ushort2v*)(cat + c0 + c) = *(const ushort2v*)(selb + r0 + c);
    *(ushort2v*)(cat + c1 + c) = *(const ushort2v*)(selb + r1 + c);
  }
}

// ---------------- weighted combine over K=2 (bf16) ----------------
__global__ void k_combine(const ushortT* __restrict__ refined, const float* __restrict__ wb,
                          ushortT* __restrict__ fin) {
  int n = blockIdx.x;
  int t = threadIdx.x;  // 192
  float w0 = wb[n * 2], w1 = wb[n * 2 + 1];
  ushort4v r0 = *(const ushort4v*)(refined + (size_t)(n * 2) * D_ + t * 4);
  ushort4v r1 = *(const ushort4v*)(refined + (size_t)(n * 2 + 1) * D_ + t * 4);
  ushort4v o;
#pragma unroll
  for (int j = 0; j < 4; ++j)
    o[j] = f2bf(w0 * bf2f(r0[j]) + w1 * bf2f(r1[j]));
  *(ushort4v*)(fin + (size_t)n * D_ + t * 4) = o;
}

__global__ void k_aux(const float* __restrict__ accs, float* __restrict__ outp) {
  if (threadIdx.x == 0) {
    float bal = 0.f;
    for (int e = 0; e < 8; ++e) bal += (accs[e] / (float)N_) * (accs[8 + e] / (float)N_);
    bal *= (float)E_;
    float z = accs[16] / (float)N_;
    float km = accs[17] / (float)NK_;
    outp[0] = 0.01f * bal + 0.001f * z + 0.001f * (1.f - km);
  }
}

// ---------------- host ----------------
extern "C" void kernel_launch(void* const* d_in, const int* in_sizes, int n_in,
                              void* d_out, int out_size, void* d_ws, size_t ws_size,
                              hipStream_t stream) {
  (void)in_sizes; (void)n_in; (void)ws_size; (void)out_size;
  const float* x = (const float*)d_in[0];
  const float* gate_w = (const float*)d_in[1];
  const float* w13 = (const float*)d_in[2];
  const float* w2 = (const float*)d_in[3];
  const float* msg_w = (const float*)d_in[4];
  const float* q_w = (const float*)d_in[5];
  const float* k_w = (const float*)d_in[6];
  const float* o_w = (const float*)d_in[7];
  const float* upd_w1 = (const float*)d_in[8];
  const float* upd_w2 = (const float*)d_in[9];

  float* ws = (float*)d_ws;
  float* accs = ws;
  int* ints = (int*)(ws + 32);
  int* cnt = ints;
  int* kcnt = ints + 8;
  int* koff = ints + 16;
  int* kpos = ints + 24;
  float* tv = ws + 64;
  float* tp = ws + 16448;
  float* wb = ws + 32832;
  int* ti = (int*)(ws + 49216);
  int* keep = (int*)(ws + 65600);
  int* bucket = (int*)(ws + 81984);
  ushortT* ub = (ushortT*)(ws + 98560);

  ushortT* w13b = ub + O_W13;
  ushortT* catb = ub + O_CAT;
  ushortT* w2b  = ub + O_W2;
  ushortT* msgb = ub + O_MSG;
  ushortT* qb   = ub + O_Q;
  ushortT* kb   = ub + O_K;
  ushortT* owb  = ub + O_OW;
  ushortT* u1b  = ub + O_U1;
  ushortT* u2b  = ub + O_U2;
  ushortT* xg   = ub + O_XG;
  ushortT* updhb= ub + O_UPDH;
  ushortT* swigb= ub + O_SWIG;
  ushortT* finb = ub + O_FIN;
  ushortT* selb = ub + O_SELB;
  ushortT* Mbb  = ub + O_MBB;
  ushortT* Qbb  = ub + O_QBB;
  ushortT* refb = ub + O_REF;
  ushortT* Ktbb = ub + O_KTB;

  float* fused = (float*)d_out;
  float* aux = fused + 6291456;
  float* idx_out = fused + 6291457;

  k_init<<<1, 64, 0, stream>>>(accs, ints);
  // weight + activation conversions
  k_cvt<<<8192, 256, 0, stream>>>(w13, w13b, 6291456);
  k_cvt<<<4096, 256, 0, stream>>>(w2, w2b, 3145728);
  k_cvt<<<576, 256, 0, stream>>>(msg_w, msgb, 147456);
  k_cvt<<<576, 256, 0, stream>>>(q_w, qb, 147456);
  k_cvt<<<576, 256, 0, stream>>>(k_w, kb, 147456);
  k_cvt<<<576, 256, 0, stream>>>(o_w, owb, 147456);
  k_cvt<<<2304, 256, 0, stream>>>(upd_w1, u1b, 589824);
  k_cvt<<<1152, 256, 0, stream>>>(upd_w2, u2b, 294912);

  k_router<<<2048, 256, 0, stream>>>(x, gate_w, tv, tp, ti, accs, cnt, idx_out);
  k_keep<<<64, 256, 0, stream>>>(tv, ti, cnt, keep, kcnt, accs);
  k_prefix<<<1, 64, 0, stream>>>(kcnt, koff);
  k_scatter<<<64, 256, 0, stream>>>(keep, ti, koff, kpos, bucket);
  k_weights<<<32, 256, 0, stream>>>(tp, keep, wb);
  k_gather<<<16384, 192, 0, stream>>>(x, bucket, kcnt, koff, xg);
  k_zero_dropped<<<16384, 192, 0, stream>>>(keep, selb);

  // ffn1: swig = swiglu((2x) @ w13[e].T)   [expert rows]
  k_bgemm<1><<<dim3(32, 256), 256, 0, stream>>>(
      xg, 768, w13b, 768, 4096ll * 768, swigb, 2048, 768, 0, 32,
      kcnt, koff, nullptr, nullptr, nullptr, nullptr);
  // ffn2: sel[slot] = x + swig @ w2[e].T   [expert rows, scatter]
  k_bgemm<2><<<dim3(6, 256), 256, 0, stream>>>(
      swigb, 2048, w2b, 2048, 768ll * 2048, selb, 768, 2048, 0, 32,
      kcnt, koff, bucket, x, nullptr, nullptr);
  // M = sel @ msg_w.T
  k_bgemm<0><<<dim3(6, 128), 256, 0, stream>>>(
      selb, 768, msgb, 768, 0, Mbb, 768, 768, 16384, 0,
      nullptr, nullptr, nullptr, nullptr, nullptr, nullptr);
  // Q = sel @ q_w.T
  k_bgemm<0><<<dim3(6, 128), 256, 0, stream>>>(
      selb, 768, qb, 768, 0, Qbb, 768, 768, 16384, 0,
      nullptr, nullptr, nullptr, nullptr, nullptr, nullptr);
  // Kt = M @ k_w.T
  k_bgemm<0><<<dim3(6, 128), 256, 0, stream>>>(
      Mbb, 768, kb, 768, 0, Ktbb, 768, 768, 16384, 0,
      nullptr, nullptr, nullptr, nullptr, nullptr, nullptr);
  k_scores_cat<<<2048, 256, 0, stream>>>(Qbb, Ktbb, Mbb, selb, keep, catb);
  // upd_h = gelu(cat @ upd_w1.T)
  k_bgemm<3><<<dim3(12, 128), 256, 0, stream>>>(
      catb, 1536, u1b, 1536, 0, updhb, 1536, 1536, 16384, 0,
      nullptr, nullptr, nullptr, nullptr, nullptr, nullptr);
  // refined = (sel + upd_h @ upd_w2.T) * km
  k_bgemm<4><<<dim3(6, 128), 256, 0, stream>>>(
      updhb, 1536, u2b, 1536, 0, refb, 768, 1536, 16384, 0,
      nullptr, nullptr, nullptr, nullptr, selb, keep);
  k_combine<<<8192, 192, 0, stream>>>(refb, wb, finb);
  // fused = fin @ o_w.T  (f32 out)
  k_bgemm<5><<<dim3(6, 64), 256, 0, stream>>>(
      finb, 768, owb, 768, 0, fused, 768, 768, 8192, 0,
      nullptr, nullptr, nullptr, nullptr, nullptr, nullptr);
  k_aux<<<1, 64, 0, stream>>>(accs, aux);
}

// Round 9
// 1037.072 us; speedup vs baseline: 4.8458x; 1.0393x over previous
//
#include <hip/hip_runtime.h>
#include <math.h>

constexpr int N_ = 8192;
constexpr int NK_ = 16384;
constexpr int D_ = 768;
constexpr int E_ = 8;
constexpr int CAP_ = 4096;
constexpr float NEG_ = -3.402823466e38f;

typedef unsigned short ushortT;
typedef __attribute__((ext_vector_type(8))) short short8v;
typedef __attribute__((ext_vector_type(4))) float float4v;
typedef __attribute__((ext_vector_type(4))) unsigned short ushort4v;
typedef __attribute__((ext_vector_type(2))) unsigned short ushort2v;

// ushort-region offsets (in ushort elements) from ub = (ushortT*)(ws + 98560)
constexpr long long O_W13 = 0;          // 25,165,824  (catb overlays after ffn1)
constexpr long long O_CAT = 0;
constexpr long long O_W2  = 25165824;   // 12,582,912
constexpr long long O_MSG = 37748736;   // 589,824
constexpr long long O_Q   = 38338560;
constexpr long long O_K   = 38928384;
constexpr long long O_OW  = 39518208;
constexpr long long O_U1  = 40108032;   // 2,359,296
constexpr long long O_U2  = 42467328;   // 1,179,648
constexpr long long O_XG  = 43646976;   // 12,582,912 (updhb overlays after ffn2)
constexpr long long O_UPDH= 43646976;   // 25,165,824
constexpr long long O_SWIG= 56229888;   // 33,554,432
constexpr long long O_FIN = 68812800;   // 6,291,456
constexpr long long O_SELB= 89784320;   // 12,582,912
constexpr long long O_MBB = 102367232;  // 12,582,912
constexpr long long O_QBB = 114950144;  // 12,582,912 (refinedb overlays)
constexpr long long O_REF = 114950144;
constexpr long long O_KTB = 127533056;  // 12,582,912

__device__ inline ushortT f2bf(float f) {
  unsigned u = __float_as_uint(f);
  unsigned r = (u + 0x7FFFu + ((u >> 16) & 1u)) >> 16;
  return (ushortT)r;
}
__device__ inline float bf2f(ushortT h) {
  return __uint_as_float(((unsigned)h) << 16);
}

// async global->LDS, 16B per lane; LDS dest = wave-uniform base + lane*16 (linear)
__device__ inline void gload16(const ushortT* g, ushortT* l) {
  __builtin_amdgcn_global_load_lds(
      (const __attribute__((address_space(1))) unsigned int*)g,
      (__attribute__((address_space(3))) unsigned int*)l, 16, 0, 0);
}

// ---------------- init ----------------
__global__ void k_init(float* accs, int* ints) {
  int t = threadIdx.x;
  if (t < 32) accs[t] = 0.f;
  if (t < 32) ints[t] = 0;
}

// ---------------- f32 -> bf16 convert ----------------
__global__ void k_cvt(const float* __restrict__ in, ushortT* __restrict__ out, int n4) {
  for (int i = blockIdx.x * 256 + threadIdx.x; i < n4; i += gridDim.x * 256) {
    float4 v = *(const float4*)(in + (size_t)i * 4);
    ushort4v o = {f2bf(v.x), f2bf(v.y), f2bf(v.z), f2bf(v.w)};
    *(ushort4v*)(out + (size_t)i * 4) = o;
  }
}

// ---------------- router (fp32) ----------------
__global__ __launch_bounds__(256) void k_router(
    const float* __restrict__ x, const float* __restrict__ gw,
    float* __restrict__ tv, float* __restrict__ tp, int* __restrict__ ti,
    float* __restrict__ accs, int* __restrict__ cnt,
    float* __restrict__ idx_out) {
  __shared__ float gws[8 * 768];
  __shared__ float rS1[8], rS2[8], rz[1];
  __shared__ int rc[8];
  int tid = threadIdx.x;
  for (int i = tid; i < 8 * 768; i += 256) gws[i] = gw[i];
  if (tid < 8) { rS1[tid] = 0.f; rS2[tid] = 0.f; rc[tid] = 0; }
  if (tid == 0) rz[0] = 0.f;
  __syncthreads();
  int wid = tid >> 6, lane = tid & 63;
  int n = blockIdx.x * 4 + wid;
  const float* xr = x + (size_t)n * D_;
  float acc[8];
#pragma unroll
  for (int e = 0; e < 8; ++e) acc[e] = 0.f;
  for (int c = 0; c < D_; c += 64) {
    float xv = xr[c + lane];
#pragma unroll
    for (int e = 0; e < 8; ++e) acc[e] = fmaf(xv, gws[e * D_ + c + lane], acc[e]);
  }
#pragma unroll
  for (int e = 0; e < 8; ++e) {
#pragma unroll
    for (int off = 32; off >= 1; off >>= 1) acc[e] += __shfl_xor(acc[e], off, 64);
  }
  if (lane == 0) {
    float v1 = NEG_; int i1 = 0;
#pragma unroll
    for (int e = 0; e < 8; ++e) if (acc[e] > v1) { v1 = acc[e]; i1 = e; }
    float v2 = NEG_; int i2 = 0;
#pragma unroll
    for (int e = 0; e < 8; ++e) if (e != i1 && acc[e] > v2) { v2 = acc[e]; i2 = e; }
    float den = 0.f; float pe[8];
#pragma unroll
    for (int e = 0; e < 8; ++e) { pe[e] = expf(acc[e] - v1); den += pe[e]; }
    float inv = 1.f / den;
#pragma unroll
    for (int e = 0; e < 8; ++e) atomicAdd(&rS1[e], pe[e] * inv);
    float z = v1 + logf(den);
    atomicAdd(&rz[0], z * z);
    float t2 = expf(v2 - v1);
    float p1 = 1.f / (1.f + t2);
    float p2 = t2 / (1.f + t2);
    atomicAdd(&rS2[i1], p1);
    atomicAdd(&rS2[i2], p2);
    atomicAdd(&rc[i1], 1);
    atomicAdd(&rc[i2], 1);
    int s0 = n * 2;
    tv[s0] = v1; tv[s0 + 1] = v2;
    tp[s0] = p1; tp[s0 + 1] = p2;
    ti[s0] = i1; ti[s0 + 1] = i2;
    idx_out[s0] = (float)i1;
    idx_out[s0 + 1] = (float)i2;
  }
  __syncthreads();
  if (tid < 8) {
    atomicAdd(&accs[tid], rS1[tid]);
    atomicAdd(&accs[8 + tid], rS2[tid]);
    atomicAdd(&cnt[tid], rc[tid]);
  }
  if (tid == 0) atomicAdd(&accs[16], rz[0]);
}

// ---------------- keep (capacity) ----------------
__global__ void k_keep(const float* __restrict__ tv, const int* __restrict__ ti,
                       const int* __restrict__ cnt, int* __restrict__ keep,
                       int* __restrict__ kcnt, float* __restrict__ accs) {
  __shared__ int kc[8]; __shared__ int ks[1];
  int tid = threadIdx.x;
  if (tid < 8) kc[tid] = 0;
  if (tid == 0) ks[0] = 0;
  __syncthreads();
  int s = blockIdx.x * 256 + tid;
  int e = ti[s];
  int kp;
  if (cnt[e] <= CAP_) kp = 1;
  else {
    float p = tv[s];
    int rank = 0;
    for (int j = 0; j < NK_; ++j) {
      if (ti[j] == e) {
        float pj = tv[j];
        if (pj > p || (pj == p && j < s)) ++rank;
      }
    }
    kp = (rank < CAP_) ? 1 : 0;
  }
  keep[s] = kp;
  atomicAdd(&kc[e], kp);
  atomicAdd(&ks[0], kp);
  __syncthreads();
  if (tid < 8) atomicAdd(&kcnt[tid], kc[tid]);
  if (tid == 0) atomicAdd(&accs[17], (float)ks[0]);
}

__global__ void k_prefix(const int* __restrict__ kcnt, int* __restrict__ koff) {
  if (threadIdx.x == 0) {
    int o = 0;
    for (int e = 0; e < 8; ++e) { koff[e] = o; o += kcnt[e]; }
  }
}

__global__ void k_scatter(const int* __restrict__ keep, const int* __restrict__ ti,
                          const int* __restrict__ koff, int* __restrict__ kpos,
                          int* __restrict__ bucket) {
  int s = blockIdx.x * 256 + threadIdx.x;
  if (keep[s]) {
    int e = ti[s];
    int pos = atomicAdd(&kpos[e], 1);
    bucket[koff[e] + pos] = s;
  }
}

__global__ void k_weights(const float* __restrict__ tp, const int* __restrict__ keep,
                          float* __restrict__ wb) {
  int n = blockIdx.x * 256 + threadIdx.x;
  if (n < N_) {
    int s = n * 2;
    float t0 = keep[s] ? tp[s] : 0.f;
    float t1 = keep[s + 1] ? tp[s + 1] : 0.f;
    float d = fmaxf(t0 + t1, 1e-12f);
    wb[s] = t0 / d; wb[s + 1] = t1 / d;
  }
}

// ---------------- gather A rows for ffn1: xg[r] = bf16(2*x[bucket[r]>>1]) ----------------
__global__ void k_gather(const float* __restrict__ x, const int* __restrict__ bucket,
                         const int* __restrict__ kcnt, const int* __restrict__ koff,
                         ushortT* __restrict__ xg) {
  int r = blockIdx.x;
  int t = threadIdx.x;  // 192
  int total = koff[7] + kcnt[7];
  size_t ob = (size_t)r * D_ + t * 4;
  if (r < total) {
    int tok = bucket[r] >> 1;
    float4 v = *(const float4*)(x + (size_t)tok * D_ + t * 4);
    ushort4v o = {f2bf(2.f * v.x), f2bf(2.f * v.y), f2bf(2.f * v.z), f2bf(2.f * v.w)};
    *(ushort4v*)(xg + ob) = o;
  } else {
    ushort4v z = {0, 0, 0, 0};
    *(ushort4v*)(xg + ob) = z;
  }
}

__global__ void k_zero_dropped(const int* __restrict__ keep, ushortT* __restrict__ selb) {
  int s = blockIdx.x;
  if (keep[s]) return;
  ushort4v z = {0, 0, 0, 0};
  *(ushort4v*)(selb + (size_t)s * D_ + threadIdx.x * 4) = z;
}

// ---------------- generic bf16 MFMA GEMM (NT), 128x128 tile, BK=64 ----------------
// Staging: global_load_lds width=16, linear LDS dest, XOR-swizzle folded into the
// per-lane GLOBAL source address (rule #21 / m173). Read side swizzled as before.
// EPI: 0 = store bf16; 1 = ffn1 swiglu (pair cols, store swig bf16, expert rows);
//      2 = ffn2 scatter (sel = x + acc, bf16, expert rows); 3 = gelu store bf16;
//      4 = refined = (selb + acc)*keep, bf16; 5 = store f32
template <int EPI>
__global__ __launch_bounds__(256) void k_bgemm(
    const ushortT* __restrict__ A, int lda,
    const ushortT* __restrict__ B, int ldb, long long bstride,
    void* __restrict__ Cp, int ldc, int Kdim, int Mrows, int tpe,
    const int* __restrict__ kcnt, const int* __restrict__ koff,
    const int* __restrict__ bucket, const float* __restrict__ xf,
    const ushortT* __restrict__ selb, const int* __restrict__ keep) {
  __shared__ __align__(16) ushortT At[128 * 64];
  __shared__ __align__(16) ushortT Bt[128 * 64];
  __shared__ int slt[128];
  int e = 0, rt = blockIdx.y, rows = Mrows, off = 0;
  if (tpe) {
    e = blockIdx.y >> 5; rt = blockIdx.y & 31;
    rows = kcnt[e]; off = koff[e];
    if (rt * 128 >= rows) return;
  }
  const int row0 = rt * 128;
  const int col0 = blockIdx.x * 128;
  const ushortT* Bb = B + (size_t)e * bstride;

  const int tid = threadIdx.x;
  if (EPI == 2) {
    if (tid < 128) slt[tid] = (row0 + tid < rows) ? bucket[off + row0 + tid] : 0;
  }

  const int l = tid & 63;
  const int wv = tid >> 6;
  // staging geometry: wave-load g covers 8 rows (1KB); lane l -> row l>>3, chunk l&7
  const int rsub = l >> 3;                       // row within 8-row group
  const int soff = ((l & 7) ^ rsub) << 3;        // pre-swizzled source chunk (elems)
  const ushortT* AsrcG[4];
  const ushortT* BsrcG[4];
#pragma unroll
  for (int g = 0; g < 4; ++g) {
    const int ga = (wv << 2) + g;                // 0..15
    const int arow = off + row0 + ga * 8 + rsub;
    AsrcG[g] = A + (size_t)arow * lda + soff;
    const int bcol = col0 + ga * 8 + rsub;
    const int brow = (EPI == 1) ? (((bcol & 1) << 11) + (bcol >> 1)) : bcol;
    BsrcG[g] = Bb + (size_t)brow * ldb + soff;
  }

  const int wr = (wv >> 1) << 6;   // wave row offset in tile
  const int wc = (wv & 1) << 6;    // wave col offset
  const int fr = l & 15;
  const int kg = l >> 4;

  float4v acc[4][4];
#pragma unroll
  for (int m = 0; m < 4; ++m)
#pragma unroll
    for (int n = 0; n < 4; ++n) acc[m][n] = (float4v){0.f, 0.f, 0.f, 0.f};

  for (int k0 = 0; k0 < Kdim; k0 += 64) {
    __syncthreads();
#pragma unroll
    for (int g = 0; g < 4; ++g) {
      const int ga = (wv << 2) + g;
      gload16(AsrcG[g] + k0, At + ga * 512);
      gload16(BsrcG[g] + k0, Bt + ga * 512);
    }
    __syncthreads();
#pragma unroll
    for (int kk = 0; kk < 2; ++kk) {
      short8v af[4], bf[4];
#pragma unroll
      for (int m = 0; m < 4; ++m) {
        int ar = wr + m * 16 + fr;
        af[m] = *(const short8v*)(At + ar * 64 + ((((kk << 2) + kg) ^ (ar & 7)) << 3));
        int br = wc + m * 16 + fr;
        bf[m] = *(const short8v*)(Bt + br * 64 + ((((kk << 2) + kg) ^ (br & 7)) << 3));
      }
#pragma unroll
      for (int m = 0; m < 4; ++m)
#pragma unroll
        for (int n = 0; n < 4; ++n)
          acc[m][n] = __builtin_amdgcn_mfma_f32_16x16x32_bf16(af[m], bf[n], acc[m][n], 0, 0, 0);
    }
  }

  // epilogue: lane holds D[row=(l>>4)*4+q][col=l&15] per fragment
#pragma unroll
  for (int m = 0; m < 4; ++m) {
#pragma unroll
    for (int q = 0; q < 4; ++q) {
      const int rl = wr + m * 16 + (kg << 2) + q;          // local row 0..127
      const bool rok = (tpe == 0) || (row0 + rl < rows);
#pragma unroll
      for (int n = 0; n < 4; ++n) {
        const int gcol = col0 + wc + n * 16 + fr;
        float v = acc[m][n][q];
        if (EPI == 0) {
          if (rok) ((ushortT*)Cp)[(size_t)(row0 + rl) * ldc + gcol] = f2bf(v);
        } else if (EPI == 1) {
          float pv = __shfl_xor(v, 1, 64);
          if ((l & 1) == 0) {
            float g = v, u = pv;
            float s = g / (1.f + expf(-g)) * u;
            if (rok)
              ((ushortT*)Cp)[(size_t)(off + row0 + rl) * ldc + (gcol >> 1)] = f2bf(s);
          }
        } else if (EPI == 2) {
          if (rok) {
            int slot = slt[rl];
            float xv = xf[(size_t)(slot >> 1) * D_ + gcol];
            ((ushortT*)Cp)[(size_t)slot * D_ + gcol] = f2bf(xv + v);
          }
        } else if (EPI == 3) {
          float gl = 0.5f * v * (1.f + erff(v * 0.70710678118654752f));
          ((ushortT*)Cp)[(size_t)(row0 + rl) * ldc + gcol] = f2bf(gl);
        } else if (EPI == 4) {
          int grow = row0 + rl;
          float sv = bf2f(selb[(size_t)grow * D_ + gcol]);
          float rr = (sv + v) * (keep[grow] ? 1.f : 0.f);
          ((ushortT*)Cp)[(size_t)grow * ldc + gcol] = f2bf(rr);
        } else if (EPI == 5) {
          ((float*)Cp)[(size_t)(row0 + rl) * ldc + gcol] = v;
        }
      }
    }
  }
}

// ---------------- per-token 2x2 attention + cat build (bf16 in/out) ----------------
__global__ __launch_bounds__(256) void k_scores_cat(
    const ushortT* __restrict__ Qb, const ushortT* __restrict__ Ktb,
    const ushortT* __restrict__ Mb, const ushortT* __restrict__ selb,
    const int* __restrict__ keep, ushortT* __restrict__ cat) {
  int tid = threadIdx.x;
  int wid = tid >> 6, lane = tid & 63;
  int n = blockIdx.x * 4 + wid;
  size_t r0 = (size_t)(n * 2) * D_;
  size_t r1 = r0 + D_;
  float s00 = 0, s01 = 0, s10 = 0, s11 = 0;
#pragma unroll
  for (int i = 0; i < 6; ++i) {
    int c = lane * 2 + i * 128;
    float q0a = bf2f(Qb[r0 + c]), q0b = bf2f(Qb[r0 + c + 1]);
    float q1a = bf2f(Qb[r1 + c]), q1b = bf2f(Qb[r1 + c + 1]);
    float k0a = bf2f(Ktb[r0 + c]), k0b = bf2f(Ktb[r0 + c + 1]);
    float k1a = bf2f(Ktb[r1 + c]), k1b = bf2f(Ktb[r1 + c + 1]);
    s00 += q0a * k0a + q0b * k0b; s01 += q0a * k1a + q0b * k1b;
    s10 += q1a * k0a + q1b * k0b; s11 += q1a * k1a + q1b * k1b;
  }
#pragma unroll
  for (int off = 32; off >= 1; off >>= 1) {
    s00 += __shfl_xor(s00, off, 64);
    s01 += __shfl_xor(s01, off, 64);
    s10 += __shfl_xor(s10, off, 64);
    s11 += __shfl_xor(s11, off, 64);
  }
  const float scl = 27.712812921102035f;  // sqrt(768)
  s00 /= scl; s01 /= scl; s10 /= scl; s11 /= scl;
  int km0 = keep[n * 2], km1 = keep[n * 2 + 1];
  float a00, a01, a10, a11;
  {
    int v0 = km0 & km0, v1 = km0 & km1;
    float t0 = v0 ? s00 : NEG_, t1 = v1 ? s01 : NEG_;
    float mx = fmaxf(t0, t1);
    float e0 = expf(t0 - mx), e1 = expf(t1 - mx);
    float sm = e0 + e1;
    float b0 = (e0 / sm) * (v0 ? 1.f : 0.f);
    float b1 = (e1 / sm) * (v1 ? 1.f : 0.f);
    float d = fmaxf(b0 + b1, 1e-12f);
    a00 = b0 / d; a01 = b1 / d;
  }
  {
    int v0 = km1 & km0, v1 = km1 & km1;
    float t0 = v0 ? s10 : NEG_, t1 = v1 ? s11 : NEG_;
    float mx = fmaxf(t0, t1);
    float e0 = expf(t0 - mx), e1 = expf(t1 - mx);
    float sm = e0 + e1;
    float b0 = (e0 / sm) * (v0 ? 1.f : 0.f);
    float b1 = (e1 / sm) * (v1 ? 1.f : 0.f);
    float d = fmaxf(b0 + b1, 1e-12f);
    a10 = b0 / d; a11 = b1 / d;
  }
  size_t c0 = (size_t)(n * 2) * 1536;
  size_t c1 = c0 + 1536;
#pragma unroll
  for (int i = 0; i < 6; ++i) {
    int c = lane * 2 + i * 128;
    float m0a = bf2f(Mb[r0 + c]), m0b = bf2f(Mb[r0 + c + 1]);
    float m1a = bf2f(Mb[r1 + c]), m1b = bf2f(Mb[r1 + c + 1]);
    ushort2v x0 = {f2bf(fmaf(a00, m0a, a01 * m1a)), f2bf(fmaf(a00, m0b, a01 * m1b))};
    ushort2v x1 = {f2bf(fmaf(a10, m0a, a11 * m1a)), f2bf(fmaf(a10, m0b, a11 * m1b))};
    *(ushort2v*)(cat + c0 + 768 + c) = x0;
    *(ushort2v*)(cat + c1 + 768 + c) = x1;
    *(ushort2v*)(cat + c0 + c) = *(const ushort2v*)(selb + r0 + c);
    *(ushort2v*)(cat + c1 + c) = *(const ushort2v*)(selb + r1 + c);
  }
}

// ---------------- weighted combine over K=2 (bf16) ----------------
__global__ void k_combine(const ushortT* __restrict__ refined, const float* __restrict__ wb,
                          ushortT* __restrict__ fin) {
  int n = blockIdx.x;
  int t = threadIdx.x;  // 192
  float w0 = wb[n * 2], w1 = wb[n * 2 + 1];
  ushort4v r0 = *(const ushort4v*)(refined + (size_t)(n * 2) * D_ + t * 4);
  ushort4v r1 = *(const ushort4v*)(refined + (size_t)(n * 2 + 1) * D_ + t * 4);
  ushort4v o;
#pragma unroll
  for (int j = 0; j < 4; ++j)
    o[j] = f2bf(w0 * bf2f(r0[j]) + w1 * bf2f(r1[j]));
  *(ushort4v*)(fin + (size_t)n * D_ + t * 4) = o;
}

__global__ void k_aux(const float* __restrict__ accs, float* __restrict__ outp) {
  if (threadIdx.x == 0) {
    float bal = 0.f;
    for (int e = 0; e < 8; ++e) bal += (accs[e] / (float)N_) * (accs[8 + e] / (float)N_);
    bal *= (float)E_;
    float z = accs[16] / (float)N_;
    float km = accs[17] / (float)NK_;
    outp[0] = 0.01f * bal + 0.001f * z + 0.001f * (1.f - km);
  }
}

// ---------------- host ----------------
extern "C" void kernel_launch(void* const* d_in, const int* in_sizes, int n_in,
                              void* d_out, int out_size, void* d_ws, size_t ws_size,
                              hipStream_t stream) {
  (void)in_sizes; (void)n_in; (void)ws_size; (void)out_size;
  const float* x = (const float*)d_in[0];
  const float* gate_w = (const float*)d_in[1];
  const float* w13 = (const float*)d_in[2];
  const float* w2 = (const float*)d_in[3];
  const float* msg_w = (const float*)d_in[4];
  const float* q_w = (const float*)d_in[5];
  const float* k_w = (const float*)d_in[6];
  const float* o_w = (const float*)d_in[7];
  const float* upd_w1 = (const float*)d_in[8];
  const float* upd_w2 = (const float*)d_in[9];

  float* ws = (float*)d_ws;
  float* accs = ws;
  int* ints = (int*)(ws + 32);
  int* cnt = ints;
  int* kcnt = ints + 8;
  int* koff = ints + 16;
  int* kpos = ints + 24;
  float* tv = ws + 64;
  float* tp = ws + 16448;
  float* wb = ws + 32832;
  int* ti = (int*)(ws + 49216);
  int* keep = (int*)(ws + 65600);
  int* bucket = (int*)(ws + 81984);
  ushortT* ub = (ushortT*)(ws + 98560);

  ushortT* w13b = ub + O_W13;
  ushortT* catb = ub + O_CAT;
  ushortT* w2b  = ub + O_W2;
  ushortT* msgb = ub + O_MSG;
  ushortT* qb   = ub + O_Q;
  ushortT* kb   = ub + O_K;
  ushortT* owb  = ub + O_OW;
  ushortT* u1b  = ub + O_U1;
  ushortT* u2b  = ub + O_U2;
  ushortT* xg   = ub + O_XG;
  ushortT* updhb= ub + O_UPDH;
  ushortT* swigb= ub + O_SWIG;
  ushortT* finb = ub + O_FIN;
  ushortT* selb = ub + O_SELB;
  ushortT* Mbb  = ub + O_MBB;
  ushortT* Qbb  = ub + O_QBB;
  ushortT* refb = ub + O_REF;
  ushortT* Ktbb = ub + O_KTB;

  float* fused = (float*)d_out;
  float* aux = fused + 6291456;
  float* idx_out = fused + 6291457;

  k_init<<<1, 64, 0, stream>>>(accs, ints);
  // weight + activation conversions
  k_cvt<<<8192, 256, 0, stream>>>(w13, w13b, 6291456);
  k_cvt<<<4096, 256, 0, stream>>>(w2, w2b, 3145728);
  k_cvt<<<576, 256, 0, stream>>>(msg_w, msgb, 147456);
  k_cvt<<<576, 256, 0, stream>>>(q_w, qb, 147456);
  k_cvt<<<576, 256, 0, stream>>>(k_w, kb, 147456);
  k_cvt<<<576, 256, 0, stream>>>(o_w, owb, 147456);
  k_cvt<<<2304, 256, 0, stream>>>(upd_w1, u1b, 589824);
  k_cvt<<<1152, 256, 0, stream>>>(upd_w2, u2b, 294912);

  k_router<<<2048, 256, 0, stream>>>(x, gate_w, tv, tp, ti, accs, cnt, idx_out);
  k_keep<<<64, 256, 0, stream>>>(tv, ti, cnt, keep, kcnt, accs);
  k_prefix<<<1, 64, 0, stream>>>(kcnt, koff);
  k_scatter<<<64, 256, 0, stream>>>(keep, ti, koff, kpos, bucket);
  k_weights<<<32, 256, 0, stream>>>(tp, keep, wb);
  k_gather<<<16384, 192, 0, stream>>>(x, bucket, kcnt, koff, xg);
  k_zero_dropped<<<16384, 192, 0, stream>>>(keep, selb);

  // ffn1: swig = swiglu((2x) @ w13[e].T)   [expert rows]
  k_bgemm<1><<<dim3(32, 256), 256, 0, stream>>>(
      xg, 768, w13b, 768, 4096ll * 768, swigb, 2048, 768, 0, 32,
      kcnt, koff, nullptr, nullptr, nullptr, nullptr);
  // ffn2: sel[slot] = x + swig @ w2[e].T   [expert rows, scatter]
  k_bgemm<2><<<dim3(6, 256), 256, 0, stream>>>(
      swigb, 2048, w2b, 2048, 768ll * 2048, selb, 768, 2048, 0, 32,
      kcnt, koff, bucket, x, nullptr, nullptr);
  // M = sel @ msg_w.T
  k_bgemm<0><<<dim3(6, 128), 256, 0, stream>>>(
      selb, 768, msgb, 768, 0, Mbb, 768, 768, 16384, 0,
      nullptr, nullptr, nullptr, nullptr, nullptr, nullptr);
  // Q = sel @ q_w.T
  k_bgemm<0><<<dim3(6, 128), 256, 0, stream>>>(
      selb, 768, qb, 768, 0, Qbb, 768, 768, 16384, 0,
      nullptr, nullptr, nullptr, nullptr, nullptr, nullptr);
  // Kt = M @ k_w.T
  k_bgemm<0><<<dim3(6, 128), 256, 0, stream>>>(
      Mbb, 768, kb, 768, 0, Ktbb, 768, 768, 16384, 0,
      nullptr, nullptr, nullptr, nullptr, nullptr, nullptr);
  k_scores_cat<<<2048, 256, 0, stream>>>(Qbb, Ktbb, Mbb, selb, keep, catb);
  // upd_h = gelu(cat @ upd_w1.T)
  k_bgemm<3><<<dim3(12, 128), 256, 0, stream>>>(
      catb, 1536, u1b, 1536, 0, updhb, 1536, 1536, 16384, 0,
      nullptr, nullptr, nullptr, nullptr, nullptr, nullptr);
  // refined = (sel + upd_h @ upd_w2.T) * km
  k_bgemm<4><<<dim3(6, 128), 256, 0, stream>>>(
      updhb, 1536, u2b, 1536, 0, refb, 768, 1536, 16384, 0,
      nullptr, nullptr, nullptr, nullptr, selb, keep);
  k_combine<<<8192, 192, 0, stream>>>(refb, wb, finb);
  // fused = fin @ o_w.T  (f32 out)
  k_bgemm<5><<<dim3(6, 64), 256, 0, stream>>>(
      finb, 768, owb, 768, 0, fused, 768, 768, 8192, 0,
      nullptr, nullptr, nullptr, nullptr, nullptr, nullptr);
  k_aux<<<1, 64, 0, stream>>>(accs, aux);
}